// Round 6
// baseline (361.113 us; speedup 1.0000x reference)
//
#include <hip/hip_runtime.h>
#include <hip/hip_bf16.h>
#include <math.h>

typedef __bf16 bf16_t;
typedef bf16_t bf16x8 __attribute__((ext_vector_type(8)));
typedef bf16_t bf16x4 __attribute__((ext_vector_type(4)));
typedef float f32x4 __attribute__((ext_vector_type(4)));
typedef unsigned int u32;

#define B_SZ 4096
#define P_HID 1024
#define H_HID 512
#define MAX_P 128
#define MAX_HE 42
#define HE_PAD 64
#define E_MAX 8128
#define E_MAX4 2032

// ---------------------------------------------------------------------------
__device__ __forceinline__ void async_cp16(const bf16_t* g, bf16_t* l) {
    __builtin_amdgcn_global_load_lds(
        (const __attribute__((address_space(1))) u32*)g,
        (__attribute__((address_space(3))) u32*)l, 16, 0, 0);
}

__device__ __forceinline__ float gelu_exact(float v) {
    return 0.5f * v * (1.f + erff(v * 0.70710678118654752f));
}

// ---------------------------------------------------------------------------
// Split-bf16 3-MFMA GEMM. A planes staged to LDS (async); B (weights, L2-hot)
// fragments loaded DIRECTLY from global to registers — no B staging, 3x less
// LDS traffic. BT planes are [Npad][K] row-major.
// Wave grid WM x WN; wave tile (BM/WM) x (BN/WN); 16x16x32 MFMA subtiles.
// MODE 0: C = gelu(acc + bias) -> split bf16 planes Chi/Clo [M][N].
// MODE 1: gumbel-hard mask + per-row count epilogue (requires BN == Npad so
//         a block holds full rows; no atomics). NV = valid cols (<= BN).
// ---------------------------------------------------------------------------
template<int BM, int BN, int WM, int WN, int MODE>
__global__ __launch_bounds__(256, 2) void gemm_f(
    const bf16_t* __restrict__ Ahi, const bf16_t* __restrict__ Alo,
    const bf16_t* __restrict__ BThi, const bf16_t* __restrict__ BTlo,
    const float* __restrict__ bias,
    bf16_t* __restrict__ Chi, bf16_t* __restrict__ Clo,
    int N, int K,
    const float* __restrict__ g, float* __restrict__ out_mask,
    float* __restrict__ out_n, int* __restrict__ ws_n, int NV)
{
    constexpr int MT = BM / (WM * 16);     // m-subtiles per wave
    constexpr int NT = BN / (WN * 16);     // n-subtiles per wave
    constexpr int AOPS = BM / 16;          // 16-row async ops per A plane

    __shared__ __align__(16) bf16_t As0[BM * 32];
    __shared__ __align__(16) bf16_t As1[BM * 32];
    __shared__ float cnt[BM][WN];          // MODE 1 cross-wave count reduce

    const int tid  = threadIdx.x;
    const int lane = tid & 63;
    const int wid  = tid >> 6;
    const int wm   = wid % WM;
    const int wn   = wid / WM;
    const int bm   = blockIdx.y * BM;
    const int bn   = blockIdx.x * BN;

    const int srow = lane >> 2;            // staging row within a 16-row op
    const int scol = (lane & 3) * 8;       // staging k-offset (bf16 elems)

    const int fr = lane & 15;
    const int fq = lane >> 4;

    f32x4 acc[MT][NT];
#pragma unroll
    for (int i = 0; i < MT; ++i)
#pragma unroll
        for (int j = 0; j < NT; ++j)
            acc[i][j] = (f32x4){0.f, 0.f, 0.f, 0.f};

    const bf16_t* const gA0 = Ahi + (size_t)bm * K;
    const bf16_t* const gA1 = Alo + (size_t)bm * K;
    // per-lane B row pointers (fragment rows in BT)
    const bf16_t* gBh[NT];
    const bf16_t* gBl[NT];
#pragma unroll
    for (int j = 0; j < NT; ++j) {
        const size_t row = (size_t)(bn + wn * (BN / WN) + j * 16 + fr);
        gBh[j] = BThi + row * K + fq * 8;
        gBl[j] = BTlo + row * K + fq * 8;
    }

    for (int kt = 0; kt < K; kt += 32) {
        __syncthreads();                   // prior-iter A frag reads done
#pragma unroll
        for (int o = 0; o < 2 * AOPS; ++o) {
            if ((o & 3) != wid) continue;
            const int plane = o / AOPS;
            const int q     = o % AOPS;
            const bf16_t* gsrc = plane ? gA1 : gA0;
            bf16_t* lbase      = plane ? As1 : As0;
            async_cp16(gsrc + (size_t)(q * 16 + srow) * K + kt + scol,
                       lbase + q * 16 * 32);
        }
        // B fragments straight from global (L2-resident weights)
        bf16x8 bh[NT], bl[NT];
#pragma unroll
        for (int j = 0; j < NT; ++j) {
            bh[j] = *(const bf16x8*)(gBh[j] + kt);
            bl[j] = *(const bf16x8*)(gBl[j] + kt);
        }
        __syncthreads();                   // vmcnt drained before barrier

        bf16x8 ah[MT], al[MT];
#pragma unroll
        for (int i = 0; i < MT; ++i) {
            const int row = wm * (BM / WM) + i * 16 + fr;
            ah[i] = *(const bf16x8*)(As0 + row * 32 + fq * 8);
            al[i] = *(const bf16x8*)(As1 + row * 32 + fq * 8);
        }
#pragma unroll
        for (int i = 0; i < MT; ++i)
#pragma unroll
            for (int j = 0; j < NT; ++j) {
                acc[i][j] = __builtin_amdgcn_mfma_f32_16x16x32_bf16(ah[i], bh[j], acc[i][j], 0, 0, 0);
                acc[i][j] = __builtin_amdgcn_mfma_f32_16x16x32_bf16(ah[i], bl[j], acc[i][j], 0, 0, 0);
                acc[i][j] = __builtin_amdgcn_mfma_f32_16x16x32_bf16(al[i], bh[j], acc[i][j], 0, 0, 0);
            }
    }

    // ---- epilogue ----  C/D layout: col = lane&15, row = (lane>>4)*4 + reg
    if (MODE == 0) {
#pragma unroll
        for (int i = 0; i < MT; ++i)
#pragma unroll
            for (int j = 0; j < NT; ++j) {
                const int col  = bn + wn * (BN / WN) + j * 16 + fr;
                const int row0 = bm + wm * (BM / WM) + i * 16 + fq * 4;
                const float bj = bias[col];
#pragma unroll
                for (int r = 0; r < 4; ++r) {
                    float v = gelu_exact(acc[i][j][r] + bj);
                    bf16_t h = (bf16_t)v;
                    bf16_t l = (bf16_t)(v - (float)h);
                    const size_t off = (size_t)(row0 + r) * N + col;
                    Chi[off] = h;
                    Clo[off] = l;
                }
            }
    } else {
        // gumbel-hard mask + per-row counts (block holds full rows: BN==Npad)
#pragma unroll
        for (int i = 0; i < MT; ++i) {
#pragma unroll
            for (int r = 0; r < 4; ++r) {
                const int row_l = wm * (BM / WM) + i * 16 + fq * 4 + r;
                const int grow  = bm + row_l;
                float s = 0.f;
#pragma unroll
                for (int j = 0; j < NT; ++j) {
                    const int col = wn * (BN / WN) + j * 16 + fr;
                    if (col < NV) {
                        const float v = acc[i][j][r] + bias[col];
                        const size_t idx = (size_t)grow * NV + col;
                        const float g0 = g[2 * idx + 0];
                        const float g1 = g[2 * idx + 1];
                        const float m = ((v + g0) > (g1 - v)) ? 1.f : 0.f;
                        out_mask[idx] = m;
                        s += m;
                    }
                }
                s += __shfl_xor(s, 1, 64);
                s += __shfl_xor(s, 2, 64);
                s += __shfl_xor(s, 4, 64);
                s += __shfl_xor(s, 8, 64);
                if (fr == 0) cnt[row_l][wn] = s;
            }
        }
        __syncthreads();
        if (tid < BM) {
            float c = 0.f;
#pragma unroll
            for (int w2 = 0; w2 < WN; ++w2) c += cnt[tid][w2];
            out_n[bm + tid] = c;
            if (ws_n) ws_n[bm + tid] = (int)c;
        }
    }
}

// ---------------------------------------------------------------------------
// prep_all: block-range dispatch. Activation splits, weight transpose+splits,
// edge_index. (No logit buffers / zero-inits needed anymore.)
// ---------------------------------------------------------------------------
struct PrepArgs {
    const float *ph, *hh, *W1p, *W2p, *W1h, *W2h;
    bf16_t *pA_hi, *pA_lo, *hA_hi, *hA_lo;
    bf16_t *W1pT_hi, *W1pT_lo, *W2pT_hi, *W2pT_lo;
    bf16_t *W1hT_hi, *W1hT_lo, *W2hT_hi, *W2hT_lo;
    float *out_ei; int *ws_jj;
};

__device__ __forceinline__ void split4(const float* x, bf16_t* hi, bf16_t* lo, int i) {
    float4 v = ((const float4*)x)[i];
    float vv[4] = {v.x, v.y, v.z, v.w};
    bf16x4 h, l;
#pragma unroll
    for (int r = 0; r < 4; ++r) {
        bf16_t hh = (bf16_t)vv[r];
        h[r] = hh;
        l[r] = (bf16_t)(vv[r] - (float)hh);
    }
    ((bf16x4*)hi)[i] = h;
    ((bf16x4*)lo)[i] = l;
}

__device__ __forceinline__ void tsplit(
    const float* W, bf16_t* Thi, bf16_t* Tlo, int K, int N,
    int t, int nx, float (*sh)[33], int tid)
{
    const int n0 = (t % nx) * 32, k0 = (t / nx) * 32;
    const int tx = tid & 31, ty = tid >> 5;
    for (int r = ty; r < 32; r += 8) {
        const int n = n0 + tx;
        sh[r][tx] = (n < N) ? W[(size_t)(k0 + r) * N + n] : 0.f;
    }
    __syncthreads();
    for (int r = ty; r < 32; r += 8) {
        const float x = sh[tx][r];     // = W[k0+tx][n0+r]
        bf16_t h = (bf16_t)x;
        bf16_t l = (bf16_t)(x - (float)h);
        const size_t off = (size_t)(n0 + r) * K + k0 + tx;
        Thi[off] = h;
        Tlo[off] = l;
    }
}

__device__ __forceinline__ int tri_off(int i) { return (i * (255 - i)) >> 1; }

// ranges: p-split 4096 | h-split 2048 | W1p 1024 | W2p 128 | W1h 256 |
//         W2h 32 | edge_idx 32   => 7616 blocks
__global__ __launch_bounds__(256) void prep_all(PrepArgs a)
{
    __shared__ float sh[32][33];
    const int bid = blockIdx.x;
    const int tid = threadIdx.x;

    if (bid < 4096) {
        split4(a.ph, a.pA_hi, a.pA_lo, bid * 256 + tid);
    } else if (bid < 6144) {
        split4(a.hh, a.hA_hi, a.hA_lo, (bid - 4096) * 256 + tid);
    } else if (bid < 7168) {
        tsplit(a.W1p, a.W1pT_hi, a.W1pT_lo, P_HID, P_HID, bid - 6144, 32, sh, tid);
    } else if (bid < 7296) {
        tsplit(a.W2p, a.W2pT_hi, a.W2pT_lo, P_HID, MAX_P, bid - 7168, 4, sh, tid);
    } else if (bid < 7552) {
        tsplit(a.W1h, a.W1hT_hi, a.W1hT_lo, H_HID, H_HID, bid - 7296, 16, sh, tid);
    } else if (bid < 7584) {
        tsplit(a.W2h, a.W2hT_hi, a.W2hT_lo, H_HID, MAX_HE, bid - 7552, 2, sh, tid);
    } else {
        const int e = (bid - 7584) * 256 + tid;
        if (e < E_MAX) {
            int i = (int)((255.0 - sqrt(65025.0 - 8.0 * (double)e)) * 0.5);
            if (i < 0) i = 0;
            if (i > 126) i = 126;
            while (i > 0 && tri_off(i) > e) --i;
            while (i < 126 && tri_off(i + 1) <= e) ++i;
            const int j = i + 1 + (e - tri_off(i));
            a.out_ei[e] = (float)i;
            a.out_ei[E_MAX + e] = (float)j;
            a.ws_jj[e] = j;
        }
    }
}

// ---------------------------------------------------------------------------
// edge_valid[b,e] = jj[e] < n_particles[b]; float4-wide, no integer division.
// grid = 2*B_SZ blocks; block handles half a row (1016 float4s).
// ---------------------------------------------------------------------------
__global__ __launch_bounds__(256) void edge_valid_kernel(
    const int* __restrict__ ws_jj, const int* __restrict__ ws_n,
    float* __restrict__ out)
{
    const int b   = blockIdx.x >> 1;
    const int seg = blockIdx.x & 1;
    const int n   = ws_n[b];
    const int base = seg * (E_MAX4 / 2);                 // 1016
    float* const orow = out + (size_t)b * E_MAX;
#pragma unroll
    for (int it = 0; it < 4; ++it) {
        const int q = base + it * 256 + threadIdx.x;
        if (q < base + E_MAX4 / 2) {
            const int4 j4 = ((const int4*)ws_jj)[q];
            float4 v;
            v.x = (j4.x < n) ? 1.f : 0.f;
            v.y = (j4.y < n) ? 1.f : 0.f;
            v.z = (j4.z < n) ? 1.f : 0.f;
            v.w = (j4.w < n) ? 1.f : 0.f;
            ((float4*)orow)[q] = v;
        }
    }
}

// ---------------------------------------------------------------------------
extern "C" void kernel_launch(void* const* d_in, const int* in_sizes, int n_in,
                              void* d_out, int out_size, void* d_ws, size_t ws_size,
                              hipStream_t stream)
{
    const float* particle_h  = (const float*)d_in[0];
    const float* hyperedge_h = (const float*)d_in[2];
    const float* g_p  = (const float*)d_in[3];
    const float* g_h  = (const float*)d_in[4];
    const float* W1_p = (const float*)d_in[5];
    const float* b1_p = (const float*)d_in[6];
    const float* W2_p = (const float*)d_in[7];
    const float* b2_p = (const float*)d_in[8];
    const float* W1_h = (const float*)d_in[9];
    const float* b1_h = (const float*)d_in[10];
    const float* W2_h = (const float*)d_in[11];
    const float* b2_h = (const float*)d_in[12];

    float* out = (float*)d_out;
    float* out_pmask = out;                                   // 4096*128
    float* out_np    = out_pmask + (size_t)B_SZ * MAX_P;      // 4096
    float* out_ei    = out_np + B_SZ;                         // 2*8128
    float* out_ev    = out_ei + 2 * E_MAX;                    // 4096*8128
    float* out_hmask = out_ev + (size_t)B_SZ * E_MAX;         // 4096*42
    float* out_nh    = out_hmask + (size_t)B_SZ * MAX_HE;     // 4096

    char* w = (char*)d_ws;
    bf16_t* pA_hi   = (bf16_t*)w;  w += (size_t)B_SZ * P_HID * 2;
    bf16_t* pA_lo   = (bf16_t*)w;  w += (size_t)B_SZ * P_HID * 2;
    bf16_t* hA_hi   = (bf16_t*)w;  w += (size_t)B_SZ * H_HID * 2;
    bf16_t* hA_lo   = (bf16_t*)w;  w += (size_t)B_SZ * H_HID * 2;
    bf16_t* hidp_hi = (bf16_t*)w;  w += (size_t)B_SZ * P_HID * 2;
    bf16_t* hidp_lo = (bf16_t*)w;  w += (size_t)B_SZ * P_HID * 2;
    bf16_t* hidh_hi = (bf16_t*)w;  w += (size_t)B_SZ * H_HID * 2;
    bf16_t* hidh_lo = (bf16_t*)w;  w += (size_t)B_SZ * H_HID * 2;
    bf16_t* W1pT_hi = (bf16_t*)w;  w += (size_t)P_HID * P_HID * 2;
    bf16_t* W1pT_lo = (bf16_t*)w;  w += (size_t)P_HID * P_HID * 2;
    bf16_t* W2pT_hi = (bf16_t*)w;  w += (size_t)MAX_P * P_HID * 2;
    bf16_t* W2pT_lo = (bf16_t*)w;  w += (size_t)MAX_P * P_HID * 2;
    bf16_t* W1hT_hi = (bf16_t*)w;  w += (size_t)H_HID * H_HID * 2;
    bf16_t* W1hT_lo = (bf16_t*)w;  w += (size_t)H_HID * H_HID * 2;
    bf16_t* W2hT_hi = (bf16_t*)w;  w += (size_t)HE_PAD * H_HID * 2;
    bf16_t* W2hT_lo = (bf16_t*)w;  w += (size_t)HE_PAD * H_HID * 2;
    int*    ws_np   = (int*)w;     w += B_SZ * 4;
    int*    ws_jj   = (int*)w;

    // ---- 1: fused prep ----
    PrepArgs pa;
    pa.ph = particle_h; pa.hh = hyperedge_h;
    pa.W1p = W1_p; pa.W2p = W2_p; pa.W1h = W1_h; pa.W2h = W2_h;
    pa.pA_hi = pA_hi; pa.pA_lo = pA_lo; pa.hA_hi = hA_hi; pa.hA_lo = hA_lo;
    pa.W1pT_hi = W1pT_hi; pa.W1pT_lo = W1pT_lo;
    pa.W2pT_hi = W2pT_hi; pa.W2pT_lo = W2pT_lo;
    pa.W1hT_hi = W1hT_hi; pa.W1hT_lo = W1hT_lo;
    pa.W2hT_hi = W2hT_hi; pa.W2hT_lo = W2hT_lo;
    pa.out_ei = out_ei; pa.ws_jj = ws_jj;
    prep_all<<<7616, 256, 0, stream>>>(pa);

    // ---- 2-3: hidden GEMMs (A staged to LDS, B direct-from-global) ----
    gemm_f<64, 128, 2, 2, 0><<<dim3(P_HID / 128, B_SZ / 64), 256, 0, stream>>>(
        pA_hi, pA_lo, W1pT_hi, W1pT_lo, b1_p, hidp_hi, hidp_lo,
        P_HID, P_HID, nullptr, nullptr, nullptr, nullptr, 0);
    gemm_f<64, 128, 2, 2, 0><<<dim3(H_HID / 128, B_SZ / 64), 256, 0, stream>>>(
        hA_hi, hA_lo, W1hT_hi, W1hT_lo, b1_h, hidh_hi, hidh_lo,
        H_HID, H_HID, nullptr, nullptr, nullptr, nullptr, 0);

    // ---- 4-5: logit GEMMs, fused gumbel mask + per-row count (full rows
    //           per block: BN == Npad, no atomics, no logit round-trip) ----
    gemm_f<32, 128, 1, 4, 1><<<dim3(1, B_SZ / 32), 256, 0, stream>>>(
        hidp_hi, hidp_lo, W2pT_hi, W2pT_lo, b2_p, nullptr, nullptr,
        MAX_P, P_HID, g_p, out_pmask, out_np, ws_np, MAX_P);
    gemm_f<64, 64, 2, 2, 1><<<dim3(1, B_SZ / 64), 256, 0, stream>>>(
        hidh_hi, hidh_lo, W2hT_hi, W2hT_lo, b2_h, nullptr, nullptr,
        HE_PAD, H_HID, g_h, out_hmask, out_nh, nullptr, MAX_HE);

    // ---- 6: edge_valid ----
    edge_valid_kernel<<<2 * B_SZ, 256, 0, stream>>>(ws_jj, ws_np, out_ev);
}

// Round 7
// 290.446 us; speedup vs baseline: 1.2433x; 1.2433x over previous
//
#include <hip/hip_runtime.h>
#include <hip/hip_bf16.h>
#include <math.h>

typedef __bf16 bf16_t;
typedef bf16_t bf16x8 __attribute__((ext_vector_type(8)));
typedef bf16_t bf16x4 __attribute__((ext_vector_type(4)));
typedef float f32x4 __attribute__((ext_vector_type(4)));
typedef unsigned int u32;

#define B_SZ 4096
#define P_HID 1024
#define H_HID 512
#define MAX_P 128
#define MAX_HE 42
#define HE_PAD 128          // W2h BT padded to 128 rows so G2h shares G2p's shape
#define E_MAX 8128
#define E_MAX4 2032

// ---------------------------------------------------------------------------
__device__ __forceinline__ void async_cp16(const bf16_t* g, bf16_t* l) {
    __builtin_amdgcn_global_load_lds(
        (const __attribute__((address_space(1))) u32*)g,
        (__attribute__((address_space(3))) u32*)l, 16, 0, 0);
}

__device__ __forceinline__ float gelu_exact(float v) {
    return 0.5f * v * (1.f + erff(v * 0.70710678118654752f));
}

// ---------------------------------------------------------------------------
// Packed split-bf16 3-MFMA GEMM (all operands staged to LDS — the measured-
// best R2/R3 structure). Two independent problems (p-branch, h-branch) share
// one dispatch; blocks [0,pBlocks) run problem P, the rest run problem H.
// BM=64, BN=128, BK=32, 4 waves in 2x2; wave tile 32x64 of 16x16x32 subtiles.
// MODE 0: C = gelu(acc+bias) -> split bf16 planes.
// MODE 1: full-row blocks (BN == Npad): gumbel-hard mask + per-row count,
//         cross-wave reduce in LDS, no atomics. NV = valid cols.
// ---------------------------------------------------------------------------
struct GemmP {
    const bf16_t *Ahi, *Alo, *BThi, *BTlo;
    const float* bias;
    bf16_t *Chi, *Clo;            // MODE 0
    const float* g;               // MODE 1
    float *out_mask, *out_n;      // MODE 1
    int *ws_n;                    // MODE 1 (optional)
    int N, K, NV, nx;             // nx = blocks along N
};

template<int MODE>
__global__ __launch_bounds__(256, 4) void gemm_pack(GemmP P, GemmP H, int pBlocks)
{
    constexpr int BM = 64, BN = 128;
    constexpr int MT = 2, NT = 4;          // wave tile 32 x 64
    constexpr int OPS_A = BM / 16;         // 4 per plane
    constexpr int OPS_B = BN / 16;         // 8 per plane
    constexpr int NOPS = 2 * OPS_A + 2 * OPS_B;   // 24, round-robin over 4 waves

    __shared__ __align__(16) bf16_t smem[(2 * BM + 2 * BN) * 32];
    __shared__ float cnt[BM][2];
    bf16_t* const As0 = smem;
    bf16_t* const As1 = smem + BM * 32;
    bf16_t* const Bs0 = smem + 2 * BM * 32;
    bf16_t* const Bs1 = smem + 2 * BM * 32 + BN * 32;

    const bool isP = (int)blockIdx.x < pBlocks;
    const GemmP& a = isP ? P : H;
    const int bid  = isP ? blockIdx.x : blockIdx.x - pBlocks;
    const int bn   = (bid % a.nx) * BN;
    const int bm   = (bid / a.nx) * BM;
    const int K    = a.K;

    const int tid  = threadIdx.x;
    const int lane = tid & 63;
    const int wid  = tid >> 6;
    const int wm   = wid & 1;
    const int wn   = wid >> 1;

    const int srow = lane >> 2;            // staging row within a 16-row op
    const int scol = (lane & 3) * 8;       // staging k-offset (bf16 elems)
    const int fr   = lane & 15;
    const int fq   = lane >> 4;

    f32x4 acc[MT][NT];
#pragma unroll
    for (int i = 0; i < MT; ++i)
#pragma unroll
        for (int j = 0; j < NT; ++j)
            acc[i][j] = (f32x4){0.f, 0.f, 0.f, 0.f};

    const bf16_t* const gA0 = a.Ahi  + (size_t)bm * K;
    const bf16_t* const gA1 = a.Alo  + (size_t)bm * K;
    const bf16_t* const gB0 = a.BThi + (size_t)bn * K;
    const bf16_t* const gB1 = a.BTlo + (size_t)bn * K;

    for (int kt = 0; kt < K; kt += 32) {
        __syncthreads();
#pragma unroll
        for (int o = 0; o < NOPS; ++o) {
            if ((o & 3) != wid) continue;
            const bf16_t* gsrc;
            bf16_t* lbase;
            int q;
            if (o < OPS_A)                  { q = o;                     gsrc = gA0; lbase = As0; }
            else if (o < 2 * OPS_A)         { q = o - OPS_A;             gsrc = gA1; lbase = As1; }
            else if (o < 2 * OPS_A + OPS_B) { q = o - 2 * OPS_A;         gsrc = gB0; lbase = Bs0; }
            else                            { q = o - 2 * OPS_A - OPS_B; gsrc = gB1; lbase = Bs1; }
            async_cp16(gsrc + (size_t)(q * 16 + srow) * K + kt + scol,
                       lbase + q * 16 * 32);
        }
        __syncthreads();

        bf16x8 ah[MT], al[MT], bh[NT], bl[NT];
#pragma unroll
        for (int i = 0; i < MT; ++i) {
            const int row = wm * 32 + i * 16 + fr;
            ah[i] = *(const bf16x8*)(As0 + row * 32 + fq * 8);
            al[i] = *(const bf16x8*)(As1 + row * 32 + fq * 8);
        }
#pragma unroll
        for (int j = 0; j < NT; ++j) {
            const int row = wn * 64 + j * 16 + fr;
            bh[j] = *(const bf16x8*)(Bs0 + row * 32 + fq * 8);
            bl[j] = *(const bf16x8*)(Bs1 + row * 32 + fq * 8);
        }
#pragma unroll
        for (int i = 0; i < MT; ++i)
#pragma unroll
            for (int j = 0; j < NT; ++j) {
                acc[i][j] = __builtin_amdgcn_mfma_f32_16x16x32_bf16(ah[i], bh[j], acc[i][j], 0, 0, 0);
                acc[i][j] = __builtin_amdgcn_mfma_f32_16x16x32_bf16(ah[i], bl[j], acc[i][j], 0, 0, 0);
                acc[i][j] = __builtin_amdgcn_mfma_f32_16x16x32_bf16(al[i], bh[j], acc[i][j], 0, 0, 0);
            }
    }

    // ---- epilogue ----  C/D layout: col = lane&15, row = (lane>>4)*4 + reg
    if (MODE == 0) {
#pragma unroll
        for (int i = 0; i < MT; ++i)
#pragma unroll
            for (int j = 0; j < NT; ++j) {
                const int col  = bn + wn * 64 + j * 16 + fr;
                const int row0 = bm + wm * 32 + i * 16 + fq * 4;
                const float bj = a.bias[col];
#pragma unroll
                for (int r = 0; r < 4; ++r) {
                    float v = gelu_exact(acc[i][j][r] + bj);
                    bf16_t h = (bf16_t)v;
                    bf16_t l = (bf16_t)(v - (float)h);
                    const size_t off = (size_t)(row0 + r) * a.N + col;
                    a.Chi[off] = h;
                    a.Clo[off] = l;
                }
            }
    } else {
        // full rows per block (bn == 0, BN == Npad): mask + count, no atomics
        const int NV = a.NV;
#pragma unroll
        for (int i = 0; i < MT; ++i) {
#pragma unroll
            for (int r = 0; r < 4; ++r) {
                const int row_l = wm * 32 + i * 16 + fq * 4 + r;
                const int grow  = bm + row_l;
                float s = 0.f;
#pragma unroll
                for (int j = 0; j < NT; ++j) {
                    const int col = wn * 64 + j * 16 + fr;
                    if (col < NV) {
                        const float v = acc[i][j][r] + a.bias[col];
                        const size_t idx = (size_t)grow * NV + col;
                        const float g0 = a.g[2 * idx + 0];
                        const float g1 = a.g[2 * idx + 1];
                        const float m = ((v + g0) > (g1 - v)) ? 1.f : 0.f;
                        a.out_mask[idx] = m;
                        s += m;
                    }
                }
                s += __shfl_xor(s, 1, 64);
                s += __shfl_xor(s, 2, 64);
                s += __shfl_xor(s, 4, 64);
                s += __shfl_xor(s, 8, 64);
                if (fr == 0) cnt[row_l][wn] = s;
            }
        }
        __syncthreads();
        if (tid < BM) {
            const float c = cnt[tid][0] + cnt[tid][1];
            a.out_n[bm + tid] = c;
            if (a.ws_n) a.ws_n[bm + tid] = (int)c;
        }
    }
}

// ---------------------------------------------------------------------------
// prep_all: block-range dispatch. Activation splits, weight transpose+splits
// (W2h padded to 128 rows), edge_index.
// ---------------------------------------------------------------------------
struct PrepArgs {
    const float *ph, *hh, *W1p, *W2p, *W1h, *W2h;
    bf16_t *pA_hi, *pA_lo, *hA_hi, *hA_lo;
    bf16_t *W1pT_hi, *W1pT_lo, *W2pT_hi, *W2pT_lo;
    bf16_t *W1hT_hi, *W1hT_lo, *W2hT_hi, *W2hT_lo;
    float *out_ei; int *ws_jj;
};

__device__ __forceinline__ void split4(const float* x, bf16_t* hi, bf16_t* lo, int i) {
    float4 v = ((const float4*)x)[i];
    float vv[4] = {v.x, v.y, v.z, v.w};
    bf16x4 h, l;
#pragma unroll
    for (int r = 0; r < 4; ++r) {
        bf16_t hh = (bf16_t)vv[r];
        h[r] = hh;
        l[r] = (bf16_t)(vv[r] - (float)hh);
    }
    ((bf16x4*)hi)[i] = h;
    ((bf16x4*)lo)[i] = l;
}

__device__ __forceinline__ void tsplit(
    const float* W, bf16_t* Thi, bf16_t* Tlo, int K, int N,
    int t, int nx, float (*sh)[33], int tid)
{
    const int n0 = (t % nx) * 32, k0 = (t / nx) * 32;
    const int tx = tid & 31, ty = tid >> 5;
    for (int r = ty; r < 32; r += 8) {
        const int n = n0 + tx;
        sh[r][tx] = (n < N) ? W[(size_t)(k0 + r) * N + n] : 0.f;
    }
    __syncthreads();
    for (int r = ty; r < 32; r += 8) {
        const float x = sh[tx][r];     // = W[k0+tx][n0+r]
        bf16_t h = (bf16_t)x;
        bf16_t l = (bf16_t)(x - (float)h);
        const size_t off = (size_t)(n0 + r) * K + k0 + tx;
        Thi[off] = h;
        Tlo[off] = l;
    }
}

__device__ __forceinline__ int tri_off(int i) { return (i * (255 - i)) >> 1; }

// ranges: p-split 4096 | h-split 2048 | W1p 1024 | W2p 128 | W1h 256 |
//         W2h(pad128) 64 | edge_idx 32   => 7648 blocks
__global__ __launch_bounds__(256) void prep_all(PrepArgs a)
{
    __shared__ float sh[32][33];
    const int bid = blockIdx.x;
    const int tid = threadIdx.x;

    if (bid < 4096) {
        split4(a.ph, a.pA_hi, a.pA_lo, bid * 256 + tid);
    } else if (bid < 6144) {
        split4(a.hh, a.hA_hi, a.hA_lo, (bid - 4096) * 256 + tid);
    } else if (bid < 7168) {
        tsplit(a.W1p, a.W1pT_hi, a.W1pT_lo, P_HID, P_HID, bid - 6144, 32, sh, tid);
    } else if (bid < 7296) {
        tsplit(a.W2p, a.W2pT_hi, a.W2pT_lo, P_HID, MAX_P, bid - 7168, 4, sh, tid);
    } else if (bid < 7552) {
        tsplit(a.W1h, a.W1hT_hi, a.W1hT_lo, H_HID, H_HID, bid - 7296, 16, sh, tid);
    } else if (bid < 7616) {
        tsplit(a.W2h, a.W2hT_hi, a.W2hT_lo, H_HID, MAX_HE, bid - 7552, 4, sh, tid);
    } else {
        const int e = (bid - 7616) * 256 + tid;
        if (e < E_MAX) {
            int i = (int)((255.0 - sqrt(65025.0 - 8.0 * (double)e)) * 0.5);
            if (i < 0) i = 0;
            if (i > 126) i = 126;
            while (i > 0 && tri_off(i) > e) --i;
            while (i < 126 && tri_off(i + 1) <= e) ++i;
            const int j = i + 1 + (e - tri_off(i));
            a.out_ei[e] = (float)i;
            a.out_ei[E_MAX + e] = (float)j;
            a.ws_jj[e] = j;
        }
    }
}

// ---------------------------------------------------------------------------
// edge_valid[b,e] = jj[e] < n_particles[b]; float4-wide, no integer division.
// ---------------------------------------------------------------------------
__global__ __launch_bounds__(256) void edge_valid_kernel(
    const int* __restrict__ ws_jj, const int* __restrict__ ws_n,
    float* __restrict__ out)
{
    const int b   = blockIdx.x >> 1;
    const int seg = blockIdx.x & 1;
    const int n   = ws_n[b];
    const int base = seg * (E_MAX4 / 2);                 // 1016
    float* const orow = out + (size_t)b * E_MAX;
#pragma unroll
    for (int it = 0; it < 4; ++it) {
        const int q = base + it * 256 + threadIdx.x;
        if (q < base + E_MAX4 / 2) {
            const int4 j4 = ((const int4*)ws_jj)[q];
            float4 v;
            v.x = (j4.x < n) ? 1.f : 0.f;
            v.y = (j4.y < n) ? 1.f : 0.f;
            v.z = (j4.z < n) ? 1.f : 0.f;
            v.w = (j4.w < n) ? 1.f : 0.f;
            ((float4*)orow)[q] = v;
        }
    }
}

// ---------------------------------------------------------------------------
extern "C" void kernel_launch(void* const* d_in, const int* in_sizes, int n_in,
                              void* d_out, int out_size, void* d_ws, size_t ws_size,
                              hipStream_t stream)
{
    const float* particle_h  = (const float*)d_in[0];
    const float* hyperedge_h = (const float*)d_in[2];
    const float* g_p  = (const float*)d_in[3];
    const float* g_h  = (const float*)d_in[4];
    const float* W1_p = (const float*)d_in[5];
    const float* b1_p = (const float*)d_in[6];
    const float* W2_p = (const float*)d_in[7];
    const float* b2_p = (const float*)d_in[8];
    const float* W1_h = (const float*)d_in[9];
    const float* b1_h = (const float*)d_in[10];
    const float* W2_h = (const float*)d_in[11];
    const float* b2_h = (const float*)d_in[12];

    float* out = (float*)d_out;
    float* out_pmask = out;                                   // 4096*128
    float* out_np    = out_pmask + (size_t)B_SZ * MAX_P;      // 4096
    float* out_ei    = out_np + B_SZ;                         // 2*8128
    float* out_ev    = out_ei + 2 * E_MAX;                    // 4096*8128
    float* out_hmask = out_ev + (size_t)B_SZ * E_MAX;         // 4096*42
    float* out_nh    = out_hmask + (size_t)B_SZ * MAX_HE;     // 4096

    char* w = (char*)d_ws;
    bf16_t* pA_hi   = (bf16_t*)w;  w += (size_t)B_SZ * P_HID * 2;
    bf16_t* pA_lo   = (bf16_t*)w;  w += (size_t)B_SZ * P_HID * 2;
    bf16_t* hA_hi   = (bf16_t*)w;  w += (size_t)B_SZ * H_HID * 2;
    bf16_t* hA_lo   = (bf16_t*)w;  w += (size_t)B_SZ * H_HID * 2;
    bf16_t* hidp_hi = (bf16_t*)w;  w += (size_t)B_SZ * P_HID * 2;
    bf16_t* hidp_lo = (bf16_t*)w;  w += (size_t)B_SZ * P_HID * 2;
    bf16_t* hidh_hi = (bf16_t*)w;  w += (size_t)B_SZ * H_HID * 2;
    bf16_t* hidh_lo = (bf16_t*)w;  w += (size_t)B_SZ * H_HID * 2;
    bf16_t* W1pT_hi = (bf16_t*)w;  w += (size_t)P_HID * P_HID * 2;
    bf16_t* W1pT_lo = (bf16_t*)w;  w += (size_t)P_HID * P_HID * 2;
    bf16_t* W2pT_hi = (bf16_t*)w;  w += (size_t)MAX_P * P_HID * 2;
    bf16_t* W2pT_lo = (bf16_t*)w;  w += (size_t)MAX_P * P_HID * 2;
    bf16_t* W1hT_hi = (bf16_t*)w;  w += (size_t)H_HID * H_HID * 2;
    bf16_t* W1hT_lo = (bf16_t*)w;  w += (size_t)H_HID * H_HID * 2;
    bf16_t* W2hT_hi = (bf16_t*)w;  w += (size_t)HE_PAD * H_HID * 2;
    bf16_t* W2hT_lo = (bf16_t*)w;  w += (size_t)HE_PAD * H_HID * 2;
    int*    ws_np   = (int*)w;     w += B_SZ * 4;
    int*    ws_jj   = (int*)w;

    // ---- 1: fused prep ----
    PrepArgs pa;
    pa.ph = particle_h; pa.hh = hyperedge_h;
    pa.W1p = W1_p; pa.W2p = W2_p; pa.W1h = W1_h; pa.W2h = W2_h;
    pa.pA_hi = pA_hi; pa.pA_lo = pA_lo; pa.hA_hi = hA_hi; pa.hA_lo = hA_lo;
    pa.W1pT_hi = W1pT_hi; pa.W1pT_lo = W1pT_lo;
    pa.W2pT_hi = W2pT_hi; pa.W2pT_lo = W2pT_lo;
    pa.W1hT_hi = W1hT_hi; pa.W1hT_lo = W1hT_lo;
    pa.W2hT_hi = W2hT_hi; pa.W2hT_lo = W2hT_lo;
    pa.out_ei = out_ei; pa.ws_jj = ws_jj;
    prep_all<<<7648, 256, 0, stream>>>(pa);

    // ---- 2: packed hidden GEMMs (p: 512 blocks, h: 256 blocks) ----
    {
        GemmP P = {}, H = {};
        P.Ahi = pA_hi;  P.Alo = pA_lo;  P.BThi = W1pT_hi; P.BTlo = W1pT_lo;
        P.bias = b1_p;  P.Chi = hidp_hi; P.Clo = hidp_lo;
        P.N = P_HID; P.K = P_HID; P.nx = P_HID / 128;         // 8 -> 512 blocks
        H.Ahi = hA_hi;  H.Alo = hA_lo;  H.BThi = W1hT_hi; H.BTlo = W1hT_lo;
        H.bias = b1_h;  H.Chi = hidh_hi; H.Clo = hidh_lo;
        H.N = H_HID; H.K = H_HID; H.nx = H_HID / 128;         // 4 -> 256 blocks
        const int pB = (B_SZ / 64) * P.nx;                    // 512
        const int hB = (B_SZ / 64) * H.nx;                    // 256
        gemm_pack<0><<<pB + hB, 256, 0, stream>>>(P, H, pB);
    }

    // ---- 3: packed logit GEMMs + fused gumbel mask/count ----
    {
        GemmP P = {}, H = {};
        P.Ahi = hidp_hi; P.Alo = hidp_lo; P.BThi = W2pT_hi; P.BTlo = W2pT_lo;
        P.bias = b2_p; P.g = g_p; P.out_mask = out_pmask; P.out_n = out_np;
        P.ws_n = ws_np; P.N = MAX_P; P.K = P_HID; P.NV = MAX_P; P.nx = 1;
        H.Ahi = hidh_hi; H.Alo = hidh_lo; H.BThi = W2hT_hi; H.BTlo = W2hT_lo;
        H.bias = b2_h; H.g = g_h; H.out_mask = out_hmask; H.out_n = out_nh;
        H.ws_n = nullptr; H.N = HE_PAD; H.K = H_HID; H.NV = MAX_HE; H.nx = 1;
        const int pB = B_SZ / 64;                             // 64
        const int hB = B_SZ / 64;                             // 64
        gemm_pack<1><<<pB + hB, 256, 0, stream>>>(P, H, pB);
    }

    // ---- 4: edge_valid ----
    edge_valid_kernel<<<2 * B_SZ, 256, 0, stream>>>(ws_jj, ws_np, out_ev);
}